// Round 8
// baseline (309.591 us; speedup 1.0000x reference)
//
#include <hip/hip_runtime.h>
#include <math.h>

#define NROWS 262144
#define NBLK  2048
#define NTHR  256
#define LOG2PI_F 1.8378770664093453f
#define L2E_F   1.4426950408889634f
#define LN2_F   0.6931471805599453f

#define EXP2F(x) __builtin_amdgcn_exp2f(x)
#define LOG2F(x) __builtin_amdgcn_logf(x)

// ws float layout: wacc[2048]@0 | wzs[2048]@2048 | wmn[32768]@4096 | wmx[32768]@36864 | cons[256]@69632
#define WS_ZS   2048
#define WS_MN   4096
#define WS_MX   36864
#define WS_CONS 69632

template<int CTRL>
__device__ __forceinline__ float dppf(float x){
  return __int_as_float(__builtin_amdgcn_update_dpp(0, __float_as_int(x), CTRL, 0xF, 0xF, true));
}
__device__ __forceinline__ float rl63(float x){
  return __int_as_float(__builtin_amdgcn_readlane(__float_as_int(x), 63));
}
__device__ __forceinline__ float wsum(float x){
  x += dppf<0x111>(x); x += dppf<0x112>(x); x += dppf<0x114>(x); x += dppf<0x118>(x);
  x += dppf<0x142>(x); x += dppf<0x143>(x);
  return rl63(x);
}

// per-k constants: {Elpk, ir*L2E, Dk*L2E, Bk*L2E}
__global__ void setup_k(const float* __restrict__ mu, const float* __restrict__ pi,
                        const float* __restrict__ rr, float* __restrict__ ws){
  int k = threadIdx.x;                       // 64 threads
  float pik = pi[k], rk = rr[k];
  float mumu = 0.f;
  #pragma unroll
  for (int d = 0; d < 16; ++d){ float m = mu[k*16+d]; mumu = fmaf(m, m, mumu); }
  float lse_pi = __logf(wsum(__expf(pik)));  // pi in [0,1]: exp safe
  float lpk = pik - lse_pi;
  float ir = __expf(-rk), Bk = -0.5f*ir;
  float Dk = fmaf(Bk, mumu, -8.f*(rk + LOG2PI_F));
  float* cons = ws + WS_CONS;
  cons[k*4+0] = __expf(lpk);
  cons[k*4+1] = ir*L2E_F;
  cons[k*4+2] = Dk*L2E_F;
  cons[k*4+3] = Bk*L2E_F;
}

// wave pair shares 64 rows; wave (wid&1) handles k-half. 8 waves/SIMD occupancy.
__global__ __launch_bounds__(NTHR, 8)
void zmain(const float* __restrict__ met, const float* __restrict__ mu,
           const float* __restrict__ z, float* __restrict__ ws)
{
  __shared__ float mrg[2][64][6];            // [pair][row][{m2,sez,seu,sea,szA}] (stride 6: 2-way banks = free)
  __shared__ float scr[2116];                // smn 0..1055, smx 1056..2111, wave sums 2112..2115
  const int tid = threadIdx.x, lane = tid & 63, wid = tid >> 6;
  const int pair = wid >> 1, kh = wid & 1;
  const int bx = blockIdx.x;
  const int r = bx*128 + pair*64 + lane;     // lane <-> row

  // ---- per-dim min/max over block's 128 met rows (coalesced) ----
  float pmn[4], pmx[4];
  #pragma unroll
  for (int j=0;j<4;++j){ pmn[j]=INFINITY; pmx[j]=-INFINITY; }
  {
    const float4* mb = (const float4*)(met + (size_t)bx*2048);
    #pragma unroll
    for (int i=0;i<2;++i){
      float4 v = mb[i*256 + tid];            // slot j tracks dim (4*tid+j)&15
      pmn[0]=fminf(pmn[0],v.x); pmx[0]=fmaxf(pmx[0],v.x);
      pmn[1]=fminf(pmn[1],v.y); pmx[1]=fmaxf(pmx[1],v.y);
      pmn[2]=fminf(pmn[2],v.z); pmx[2]=fmaxf(pmx[2],v.z);
      pmn[3]=fminf(pmn[3],v.w); pmx[3]=fmaxf(pmx[3],v.w);
    }
  }

  // ---- met row into regs + ||x||^2 ----
  const float4* xr = (const float4*)(met + (size_t)r*16);
  float4 xa = xr[0], xb = xr[1], xc = xr[2], xd = xr[3];
  float xx = 0.f;
  xx=fmaf(xa.x,xa.x,xx); xx=fmaf(xa.y,xa.y,xx); xx=fmaf(xa.z,xa.z,xx); xx=fmaf(xa.w,xa.w,xx);
  xx=fmaf(xb.x,xb.x,xx); xx=fmaf(xb.y,xb.y,xx); xx=fmaf(xb.z,xb.z,xx); xx=fmaf(xb.w,xb.w,xx);
  xx=fmaf(xc.x,xc.x,xx); xx=fmaf(xc.y,xc.y,xx); xx=fmaf(xc.z,xc.z,xx); xx=fmaf(xc.w,xc.w,xx);
  xx=fmaf(xd.x,xd.x,xx); xx=fmaf(xd.y,xd.y,xx); xx=fmaf(xd.z,xd.z,xx); xx=fmaf(xd.w,xd.w,xx);

  // wave-uniform per-k constant bases for this k-half
  const float4* cons4 = (const float4*)(ws + WS_CONS) + kh*32;   // cons4[kk]
  const float4* mu4   = (const float4*)mu + kh*128;              // mu4[kk*4+q]
  const float4* zrow  = (const float4*)z + (size_t)r*16 + kh*8;  // lane's own row, 8x b128

  float sez=0.f, seu=0.f, sea=0.f, m2=-1e30f, szA=0.f;

#define STEPK(ZV, KK) { \
    float4 cc = cons4[KK]; \
    float4 M0 = mu4[(KK)*4+0], M1 = mu4[(KK)*4+1], M2v = mu4[(KK)*4+2], M3 = mu4[(KK)*4+3]; \
    float zk2 = (ZV)*L2E_F; \
    szA += (ZV); \
    sez += EXP2F(zk2); \
    seu = fmaf(cc.x, EXP2F(-0.1f*zk2), seu); \
    float dt = 0.f; \
    dt=fmaf(xa.x,M0.x,dt); dt=fmaf(xa.y,M0.y,dt); dt=fmaf(xa.z,M0.z,dt); dt=fmaf(xa.w,M0.w,dt); \
    dt=fmaf(xb.x,M1.x,dt); dt=fmaf(xb.y,M1.y,dt); dt=fmaf(xb.z,M1.z,dt); dt=fmaf(xb.w,M1.w,dt); \
    dt=fmaf(xc.x,M2v.x,dt); dt=fmaf(xc.y,M2v.y,dt); dt=fmaf(xc.z,M2v.z,dt); dt=fmaf(xc.w,M2v.w,dt); \
    dt=fmaf(xd.x,M3.x,dt); dt=fmaf(xd.y,M3.y,dt); dt=fmaf(xd.z,M3.z,dt); dt=fmaf(xd.w,M3.w,dt); \
    float t1  = fmaf(cc.w, xx, zk2); \
    float av2 = fmaf(cc.y, dt, t1) + cc.z; \
    float d2 = av2 - m2; \
    float ee = EXP2F(-fabsf(d2)); \
    bool fl = d2 > 0.f; \
    sea = fmaf(sea, fl?ee:1.f, fl?1.f:ee); \
    m2 = fmaxf(m2, av2); }

  #pragma unroll
  for (int g=0; g<8; ++g){
    float4 zq = zrow[g];                     // lane-private row: no LDS transpose needed
    STEPK(zq.x, g*4+0)
    STEPK(zq.y, g*4+1)
    STEPK(zq.z, g*4+2)
    STEPK(zq.w, g*4+3)
  }
#undef STEPK

  // ---- merge k-halves within the pair (base-2 online-softmax merge) ----
  if (kh == 1){
    mrg[pair][lane][0]=m2; mrg[pair][lane][1]=sez; mrg[pair][lane][2]=seu;
    mrg[pair][lane][3]=sea; mrg[pair][lane][4]=szA;
  }
  __syncthreads();
  float accA = 0.f, szT = 0.f;
  if (kh == 0){
    float m1 = mrg[pair][lane][0], sz1 = mrg[pair][lane][1], su1 = mrg[pair][lane][2];
    float sa1 = mrg[pair][lane][3], zz1 = mrg[pair][lane][4];
    float m = fmaxf(m2, m1);
    float seaT = fmaf(sea, EXP2F(m2 - m), sa1*EXP2F(m1 - m));
    float sezT = sez + sz1, seuT = seu + su1;
    szT = szA + zz1;
    accA = LN2_F * (fmaf(63.f, LOG2F(sezT), m + LOG2F(seaT)) - 64.f*LOG2F(seuT));
  }

  float wa = wsum(accA), wz = wsum(szT);     // nonzero only on kh==0 waves
  if (kh == 0 && lane == 0){ scr[2112 + pair] = wa; scr[2114 + pair] = wz; }
  #pragma unroll
  for (int j=0;j<4;++j){
    int d = (4*tid + j) & 15;
    scr[       d*66 + (tid>>2)] = pmn[j];
    scr[1056 + d*66 + (tid>>2)] = pmx[j];
  }
  __syncthreads();
  if (tid == 0){
    ws[bx]         = scr[2112] + scr[2113];
    ws[WS_ZS + bx] = scr[2114] + scr[2115];
  }
  if (tid < 16){
    float mnv = INFINITY, mxv = -INFINITY;
    for (int c2=0;c2<64;++c2){
      mnv = fminf(mnv, scr[tid*66+c2]);
      mxv = fmaxf(mxv, scr[1056+tid*66+c2]);
    }
    ws[WS_MN + bx*16 + tid] = mnv;
    ws[WS_MX + bx*16 + tid] = mxv;
  }
}

__global__ __launch_bounds__(NTHR)
void fin_k(const float* __restrict__ mu, const float* __restrict__ pi,
           const float* __restrict__ lam, const float* __restrict__ bp,
           const float* __restrict__ Cv,  const float* __restrict__ rr,
           const float* __restrict__ ws,  float* __restrict__ out,
           float cgam, float lamconst, float lg_c, float lg_g)
{
  __shared__ double sda[NTHR], sdz[NTHR];
  __shared__ float smn[16][66], smx[16][66];
  __shared__ float Rfin[16], vars[16];
  const int tid = threadIdx.x;

  {
    const float4* wa4 = (const float4*)ws;
    const float4* wz4 = (const float4*)(ws + WS_ZS);
    float4 a0 = wa4[tid], a1 = wa4[256 + tid];
    float4 z0 = wz4[tid], z1 = wz4[256 + tid];
    sda[tid] = (double)a0.x+(double)a0.y+(double)a0.z+(double)a0.w
             + (double)a1.x+(double)a1.y+(double)a1.z+(double)a1.w;
    sdz[tid] = (double)z0.x+(double)z0.y+(double)z0.z+(double)z0.w
             + (double)z1.x+(double)z1.y+(double)z1.z+(double)z1.w;
  }
  float pmn[4], pmx[4];
  #pragma unroll
  for (int j=0;j<4;++j){ pmn[j]=INFINITY; pmx[j]=-INFINITY; }
  {
    const float4* mn4 = (const float4*)(ws + WS_MN);
    const float4* mx4 = (const float4*)(ws + WS_MX);
    #pragma unroll
    for (int i=0;i<32;++i){
      float4 v = mn4[i*256 + tid];
      pmn[0]=fminf(pmn[0],v.x); pmn[1]=fminf(pmn[1],v.y);
      pmn[2]=fminf(pmn[2],v.z); pmn[3]=fminf(pmn[3],v.w);
      float4 w = mx4[i*256 + tid];
      pmx[0]=fmaxf(pmx[0],w.x); pmx[1]=fmaxf(pmx[1],w.y);
      pmx[2]=fmaxf(pmx[2],w.z); pmx[3]=fmaxf(pmx[3],w.w);
    }
  }
  #pragma unroll
  for (int j=0;j<4;++j){
    int d = (4*tid + j) & 15;
    smn[d][tid>>2] = pmn[j];
    smx[d][tid>>2] = pmx[j];
  }
  __syncthreads();
  for (int s = NTHR/2; s > 0; s >>= 1){
    if (tid < s){ sda[tid] += sda[tid+s]; sdz[tid] += sdz[tid+s]; }
    __syncthreads();
  }
  if (tid < 16){
    float mnv = INFINITY, mxv = -INFINITY;
    for (int c2=0;c2<64;++c2){ mnv = fminf(mnv, smn[tid][c2]); mxv = fmaxf(mxv, smx[tid][c2]); }
    float Rd = mxv - mnv;
    Rfin[tid] = Rd;
    float l = lam[tid];
    vars[tid] = l*l*Rd;
  }
  __syncthreads();

  if (tid < 64){
    int kk = tid;
    float sumR2 = 0.f;
    #pragma unroll
    for (int dd = 0; dd < 16; ++dd) sumR2 = fmaf(Rfin[dd], Rfin[dd], sumR2);
    float G = 0.025f * sqrtf(sumR2);          // c/(50g)*||R||, c=5, g=4

    float pik2 = pi[kk];
    float sp   = wsum(pik2);
    float lse2 = __logf(wsum(__expf(pik2)));
    float slogpi = sp - 64.f*lse2;

    float qsum = 0.f, slv = 0.f, bb = 0.f;
    #pragma unroll
    for (int dd = 0; dd < 16; ++dd){
      float df = mu[kk*16+dd] - bp[kk*16+dd];
      qsum += df*df / vars[dd];
      slv  += __logf(vars[dd]);
      float bv = bp[kk*16+dd];
      bb = fmaf(bv, bv, bb);
    }
    float mu_term = 0.5f*qsum + 0.5f*slv + 8.0f*LOG2PI_F;
    float rk2 = rr[kk], Ck = Cv[kk];
    float r_lp = 5.f*__logf(Ck) - 4.f*rk2 - Ck*__expf(-rk2) - lg_c;  // c=5
    float C_lp = 4.f*__logf(G)  - 3.f*Ck  - G*__expf(-Ck)  - lg_g;   // g=4
    float lam_term = 0.f;
    if (kk < 16){ float l = lam[kk]; lam_term = lamconst - 0.5f*l - 0.5f*__expf(l); }

    float per = mu_term + 0.5f*bb - r_lp - C_lp - lam_term;
    float persum = wsum(per);

    if (kk == 0){
      double zpart = sda[0] + 262144.0*(double)(cgam + slogpi) - 1.1*sdz[0];
      double tot = (double)persum
                 + (1.0 - 1.0/64.0)*(double)slogpi
                 + 512.0*(double)LOG2PI_F
                 - zpart;                     // z_loss = -zpart
      out[0] = (float)tot;
    }
  }
}

extern "C" void kernel_launch(void* const* d_in, const int* in_sizes, int n_in,
                              void* d_out, int out_size, void* d_ws, size_t ws_size,
                              hipStream_t stream) {
  const float* met = (const float*)d_in[0];
  const float* mu  = (const float*)d_in[1];
  const float* pi  = (const float*)d_in[2];
  const float* lam = (const float*)d_in[3];
  const float* bpp = (const float*)d_in[4];
  const float* Cv  = (const float*)d_in[5];
  const float* rr  = (const float*)d_in[6];
  const float* zz  = (const float*)d_in[7];
  float* out = (float*)d_out;
  float* ws  = (float*)d_ws;

  float cgam     = (float)(lgamma(64.0) + 63.0*log(0.1));
  float lamconst = (float)(0.5*log(0.5) - lgamma(0.5));
  float lg_c     = (float)lgamma(5.0);    // c = 1.25 + 15/4 = 5
  float lg_g     = (float)lgamma(4.0);    // g = 0.25 + 15/4 = 4

  setup_k<<<dim3(1), dim3(64), 0, stream>>>(mu, pi, rr, ws);
  zmain<<<dim3(NBLK), dim3(NTHR), 0, stream>>>(met, mu, zz, ws);
  fin_k<<<dim3(1), dim3(NTHR), 0, stream>>>(mu, pi, lam, bpp, Cv, rr, ws, out,
                                            cgam, lamconst, lg_c, lg_g);
}

// Round 9
// 156.855 us; speedup vs baseline: 1.9737x; 1.9737x over previous
//
#include <hip/hip_runtime.h>
#include <math.h>

#define NROWS 262144
#define NBLK  1024
#define NTHR  256
#define LOG2PI_F 1.8378770664093453f
#define L2E_F   1.4426950408889634f
#define LN2_F   0.6931471805599453f

#define EXP2F(x) __builtin_amdgcn_exp2f(x)
#define LOG2F(x) __builtin_amdgcn_logf(x)

// ws float layout: wacc[1024]@0 | wzs[1024]@1024 | wmn[16384]@2048 | wmx[16384]@18432 | cons[256]@34816
#define WS_ZS   1024
#define WS_MN   2048
#define WS_MX   18432
#define WS_CONS 34816

template<int CTRL>
__device__ __forceinline__ float dppf(float x){
  return __int_as_float(__builtin_amdgcn_update_dpp(0, __float_as_int(x), CTRL, 0xF, 0xF, true));
}
__device__ __forceinline__ float rl63(float x){
  return __int_as_float(__builtin_amdgcn_readlane(__float_as_int(x), 63));
}
__device__ __forceinline__ float wsum(float x){
  x += dppf<0x111>(x); x += dppf<0x112>(x); x += dppf<0x114>(x); x += dppf<0x118>(x);
  x += dppf<0x142>(x); x += dppf<0x143>(x);
  return rl63(x);
}

// per-k constants: {Elpk, ir*L2E, Dk*L2E, Bk*L2E}
__global__ void setup_k(const float* __restrict__ mu, const float* __restrict__ pi,
                        const float* __restrict__ rr, float* __restrict__ ws){
  int k = threadIdx.x;                       // 64 threads
  float pik = pi[k], rk = rr[k];
  float mumu = 0.f;
  #pragma unroll
  for (int d = 0; d < 16; ++d){ float m = mu[k*16+d]; mumu = fmaf(m, m, mumu); }
  float lse_pi = __logf(wsum(__expf(pik)));  // pi in [0,1]: exp safe
  float lpk = pik - lse_pi;
  float ir = __expf(-rk), Bk = -0.5f*ir;
  float Dk = fmaf(Bk, mumu, -8.f*(rk + LOG2PI_F));
  float* cons = ws + WS_CONS;
  cons[k*4+0] = __expf(lpk);
  cons[k*4+1] = ir*L2E_F;
  cons[k*4+2] = Dk*L2E_F;
  cons[k*4+3] = Bk*L2E_F;
}

// lane = row; z consumed via per-wave [64][17] LDS tile in 4 chunks of 16 k.
// smem reused as block-reduction scratch after a barrier. 8 blocks/CU.
__global__ __launch_bounds__(NTHR, 8)
void zmain(const float* __restrict__ met, const float* __restrict__ mu,
           const float* __restrict__ z, float* __restrict__ ws)
{
  __shared__ float smem[4352];               // 4 wave-tiles [64][17]; >=2116 for scr reuse
  const int tid = threadIdx.x, lane = tid & 63, wid = tid >> 6;
  const int bx = blockIdx.x;
  float* zt = smem + wid*1088;

  // ---- pass 1: per-dim min/max over this block's 256 met rows (coalesced) ----
  float pmn[4], pmx[4];
  #pragma unroll
  for (int j=0;j<4;++j){ pmn[j]=INFINITY; pmx[j]=-INFINITY; }
  {
    const float4* mb = (const float4*)(met + (size_t)bx*4096);
    #pragma unroll
    for (int i=0;i<4;++i){
      float4 v = mb[i*256 + tid];            // slot j tracks dim (4*tid+j)&15
      pmn[0]=fminf(pmn[0],v.x); pmx[0]=fmaxf(pmx[0],v.x);
      pmn[1]=fminf(pmn[1],v.y); pmx[1]=fmaxf(pmx[1],v.y);
      pmn[2]=fminf(pmn[2],v.z); pmx[2]=fmaxf(pmx[2],v.z);
      pmn[3]=fminf(pmn[3],v.w); pmx[3]=fmaxf(pmx[3],v.w);
    }
  }

  const int rw0 = bx*256 + wid*64;           // wave's first row
  // ---- met row into regs + ||x||^2 (lane's own row: 64B/lane, dense) ----
  const float4* xr = (const float4*)(met + (size_t)(rw0 + lane)*16);
  float4 xa = xr[0], xb = xr[1], xc = xr[2], xd = xr[3];
  float xx = 0.f;
  xx=fmaf(xa.x,xa.x,xx); xx=fmaf(xa.y,xa.y,xx); xx=fmaf(xa.z,xa.z,xx); xx=fmaf(xa.w,xa.w,xx);
  xx=fmaf(xb.x,xb.x,xx); xx=fmaf(xb.y,xb.y,xx); xx=fmaf(xb.z,xb.z,xx); xx=fmaf(xb.w,xb.w,xx);
  xx=fmaf(xc.x,xc.x,xx); xx=fmaf(xc.y,xc.y,xx); xx=fmaf(xc.z,xc.z,xx); xx=fmaf(xc.w,xc.w,xx);
  xx=fmaf(xd.x,xd.x,xx); xx=fmaf(xd.y,xd.y,xx); xx=fmaf(xd.z,xd.z,xx); xx=fmaf(xd.w,xd.w,xx);

  // ---- z chunk staging: lane l loads float4 (l&3) of tile-row (i*16 + l>>2) ----
  // per inst: 16 rows x 64B contiguous segments -> full 64B sectors, no overfetch
  const float4* z4 = (const float4*)z;
  const int rsub = lane >> 2, kq = lane & 3;
  const float4* cons4 = (const float4*)(ws + WS_CONS);  // uniform -> s_load
  const float4* mu4   = (const float4*)mu;              // uniform -> s_load

  float sez=0.f, seu=0.f, sea=0.f, m2=-1e30f, szA=0.f;
  float4 pf0, pf1, pf2, pf3;

#define LOADC(C) { \
    pf0 = z4[(size_t)(rw0 +  0 + rsub)*16 + (C)*4 + kq]; \
    pf1 = z4[(size_t)(rw0 + 16 + rsub)*16 + (C)*4 + kq]; \
    pf2 = z4[(size_t)(rw0 + 32 + rsub)*16 + (C)*4 + kq]; \
    pf3 = z4[(size_t)(rw0 + 48 + rsub)*16 + (C)*4 + kq]; }

#define STORC() { \
    int b = rsub*17 + kq*4; \
    zt[b]=pf0.x; zt[b+1]=pf0.y; zt[b+2]=pf0.z; zt[b+3]=pf0.w; b += 272; \
    zt[b]=pf1.x; zt[b+1]=pf1.y; zt[b+2]=pf1.z; zt[b+3]=pf1.w; b += 272; \
    zt[b]=pf2.x; zt[b+1]=pf2.y; zt[b+2]=pf2.z; zt[b+3]=pf2.w; b += 272; \
    zt[b]=pf3.x; zt[b+1]=pf3.y; zt[b+2]=pf3.z; zt[b+3]=pf3.w; }

#define STEPK(K) { \
    float4 cc = cons4[K]; \
    float4 M0 = mu4[(K)*4+0], M1 = mu4[(K)*4+1], M2v = mu4[(K)*4+2], M3 = mu4[(K)*4+3]; \
    float zkv = zt[lane*17 + ((K)&15)]; \
    float zk2 = zkv*L2E_F; \
    szA += zkv; \
    sez += EXP2F(zk2); \
    seu = fmaf(cc.x, EXP2F(-0.1f*zk2), seu); \
    float dt = 0.f; \
    dt=fmaf(xa.x,M0.x,dt); dt=fmaf(xa.y,M0.y,dt); dt=fmaf(xa.z,M0.z,dt); dt=fmaf(xa.w,M0.w,dt); \
    dt=fmaf(xb.x,M1.x,dt); dt=fmaf(xb.y,M1.y,dt); dt=fmaf(xb.z,M1.z,dt); dt=fmaf(xb.w,M1.w,dt); \
    dt=fmaf(xc.x,M2v.x,dt); dt=fmaf(xc.y,M2v.y,dt); dt=fmaf(xc.z,M2v.z,dt); dt=fmaf(xc.w,M2v.w,dt); \
    dt=fmaf(xd.x,M3.x,dt); dt=fmaf(xd.y,M3.y,dt); dt=fmaf(xd.z,M3.z,dt); dt=fmaf(xd.w,M3.w,dt); \
    float t1  = fmaf(cc.w, xx, zk2); \
    float av2 = fmaf(cc.y, dt, t1) + cc.z; \
    float d2 = av2 - m2; \
    float ee = EXP2F(-fabsf(d2)); \
    bool fl = d2 > 0.f; \
    sea = fmaf(sea, fl?ee:1.f, fl?1.f:ee); \
    m2 = fmaxf(m2, av2); }

  LOADC(0)
  #pragma unroll
  for (int c = 0; c < 4; ++c){
    STORC()                                   // compiler orders vs prior chunk's reads (same-wave DS)
    if (c == 0) LOADC(1)
    else if (c == 1) LOADC(2)
    else if (c == 2) LOADC(3)
    #pragma unroll
    for (int kk = 0; kk < 16; ++kk) STEPK(c*16 + kk)
  }
#undef STEPK
#undef STORC
#undef LOADC

  // ---- per-row epilogue (base-2 logs, fold ln2 once) ----
  float accA = LN2_F * (fmaf(63.f, LOG2F(sez), m2 + LOG2F(sea)) - 64.f*LOG2F(seu));

  // ---- block reduction: reuse smem as scratch (tiles dead after barrier) ----
  __syncthreads();
  float* scr = smem;                          // smn 0..1055, smx 1056..2111, waves 2112..2119
  float wa = wsum(accA), wz = wsum(szA);
  if (lane == 0){ scr[2112 + wid] = wa; scr[2116 + wid] = wz; }
  #pragma unroll
  for (int j=0;j<4;++j){
    int d = (4*tid + j) & 15;
    scr[       d*66 + (tid>>2)] = pmn[j];
    scr[1056 + d*66 + (tid>>2)] = pmx[j];
  }
  __syncthreads();
  if (tid == 0){
    ws[bx]         = scr[2112]+scr[2113]+scr[2114]+scr[2115];
    ws[WS_ZS + bx] = scr[2116]+scr[2117]+scr[2118]+scr[2119];
  }
  if (tid < 16){
    float mnv = INFINITY, mxv = -INFINITY;
    for (int c2=0;c2<64;++c2){
      mnv = fminf(mnv, scr[tid*66+c2]);
      mxv = fmaxf(mxv, scr[1056+tid*66+c2]);
    }
    ws[WS_MN + bx*16 + tid] = mnv;
    ws[WS_MX + bx*16 + tid] = mxv;
  }
}

__global__ __launch_bounds__(NTHR)
void fin_k(const float* __restrict__ mu, const float* __restrict__ pi,
           const float* __restrict__ lam, const float* __restrict__ bp,
           const float* __restrict__ Cv,  const float* __restrict__ rr,
           const float* __restrict__ ws,  float* __restrict__ out,
           float cgam, float lamconst, float lg_c, float lg_g)
{
  __shared__ double sda[NTHR], sdz[NTHR];
  __shared__ float smn[16][66], smx[16][66];
  __shared__ float Rfin[16], vars[16];
  const int tid = threadIdx.x;

  {
    const float4* wa4 = (const float4*)ws;
    const float4* wz4 = (const float4*)(ws + WS_ZS);
    float4 a = wa4[tid], zz = wz4[tid];
    sda[tid] = (double)a.x + (double)a.y + (double)a.z + (double)a.w;
    sdz[tid] = (double)zz.x + (double)zz.y + (double)zz.z + (double)zz.w;
  }
  float pmn[4], pmx[4];
  #pragma unroll
  for (int j=0;j<4;++j){ pmn[j]=INFINITY; pmx[j]=-INFINITY; }
  {
    const float4* mn4 = (const float4*)(ws + WS_MN);
    const float4* mx4 = (const float4*)(ws + WS_MX);
    #pragma unroll
    for (int i=0;i<16;++i){
      float4 v = mn4[i*256 + tid];
      pmn[0]=fminf(pmn[0],v.x); pmn[1]=fminf(pmn[1],v.y);
      pmn[2]=fminf(pmn[2],v.z); pmn[3]=fminf(pmn[3],v.w);
      float4 w = mx4[i*256 + tid];
      pmx[0]=fmaxf(pmx[0],w.x); pmx[1]=fmaxf(pmx[1],w.y);
      pmx[2]=fmaxf(pmx[2],w.z); pmx[3]=fmaxf(pmx[3],w.w);
    }
  }
  #pragma unroll
  for (int j=0;j<4;++j){
    int d = (4*tid + j) & 15;
    smn[d][tid>>2] = pmn[j];
    smx[d][tid>>2] = pmx[j];
  }
  __syncthreads();
  for (int s = NTHR/2; s > 0; s >>= 1){
    if (tid < s){ sda[tid] += sda[tid+s]; sdz[tid] += sdz[tid+s]; }
    __syncthreads();
  }
  if (tid < 16){
    float mnv = INFINITY, mxv = -INFINITY;
    for (int c2=0;c2<64;++c2){ mnv = fminf(mnv, smn[tid][c2]); mxv = fmaxf(mxv, smx[tid][c2]); }
    float Rd = mxv - mnv;
    Rfin[tid] = Rd;
    float l = lam[tid];
    vars[tid] = l*l*Rd;
  }
  __syncthreads();

  if (tid < 64){
    int kk = tid;
    float sumR2 = 0.f;
    #pragma unroll
    for (int dd = 0; dd < 16; ++dd) sumR2 = fmaf(Rfin[dd], Rfin[dd], sumR2);
    float G = 0.025f * sqrtf(sumR2);          // c/(50g)*||R||, c=5, g=4

    float pik2 = pi[kk];
    float sp   = wsum(pik2);
    float lse2 = __logf(wsum(__expf(pik2)));
    float slogpi = sp - 64.f*lse2;

    float qsum = 0.f, slv = 0.f, bb = 0.f;
    #pragma unroll
    for (int dd = 0; dd < 16; ++dd){
      float df = mu[kk*16+dd] - bp[kk*16+dd];
      qsum += df*df / vars[dd];
      slv  += __logf(vars[dd]);
      float bv = bp[kk*16+dd];
      bb = fmaf(bv, bv, bb);
    }
    float mu_term = 0.5f*qsum + 0.5f*slv + 8.0f*LOG2PI_F;
    float rk2 = rr[kk], Ck = Cv[kk];
    float r_lp = 5.f*__logf(Ck) - 4.f*rk2 - Ck*__expf(-rk2) - lg_c;  // c=5
    float C_lp = 4.f*__logf(G)  - 3.f*Ck  - G*__expf(-Ck)  - lg_g;   // g=4
    float lam_term = 0.f;
    if (kk < 16){ float l = lam[kk]; lam_term = lamconst - 0.5f*l - 0.5f*__expf(l); }

    float per = mu_term + 0.5f*bb - r_lp - C_lp - lam_term;
    float persum = wsum(per);

    if (kk == 0){
      double zpart = sda[0] + 262144.0*(double)(cgam + slogpi) - 1.1*sdz[0];
      double tot = (double)persum
                 + (1.0 - 1.0/64.0)*(double)slogpi
                 + 512.0*(double)LOG2PI_F
                 - zpart;                     // z_loss = -zpart
      out[0] = (float)tot;
    }
  }
}

extern "C" void kernel_launch(void* const* d_in, const int* in_sizes, int n_in,
                              void* d_out, int out_size, void* d_ws, size_t ws_size,
                              hipStream_t stream) {
  const float* met = (const float*)d_in[0];
  const float* mu  = (const float*)d_in[1];
  const float* pi  = (const float*)d_in[2];
  const float* lam = (const float*)d_in[3];
  const float* bpp = (const float*)d_in[4];
  const float* Cv  = (const float*)d_in[5];
  const float* rr  = (const float*)d_in[6];
  const float* zz  = (const float*)d_in[7];
  float* out = (float*)d_out;
  float* ws  = (float*)d_ws;

  float cgam     = (float)(lgamma(64.0) + 63.0*log(0.1));
  float lamconst = (float)(0.5*log(0.5) - lgamma(0.5));
  float lg_c     = (float)lgamma(5.0);    // c = 1.25 + 15/4 = 5
  float lg_g     = (float)lgamma(4.0);    // g = 0.25 + 15/4 = 4

  setup_k<<<dim3(1), dim3(64), 0, stream>>>(mu, pi, rr, ws);
  zmain<<<dim3(NBLK), dim3(NTHR), 0, stream>>>(met, mu, zz, ws);
  fin_k<<<dim3(1), dim3(NTHR), 0, stream>>>(mu, pi, lam, bpp, Cv, rr, ws, out,
                                            cgam, lamconst, lg_c, lg_g);
}

// Round 10
// 138.973 us; speedup vs baseline: 2.2277x; 1.1287x over previous
//
#include <hip/hip_runtime.h>
#include <math.h>

#define NROWS 262144
#define NBLK  1024
#define NTHR  256
#define LOG2PI_F 1.8378770664093453f
#define L2E_F   1.4426950408889634f
#define LN2_F   0.6931471805599453f

#define EXP2F(x) __builtin_amdgcn_exp2f(x)
#define LOG2F(x) __builtin_amdgcn_logf(x)

// ws float layout: wacc[1024]@0 | wzs[1024]@1024 | wmn[16384]@2048 | wmx[16384]@18432 | cons[256]@34816
#define WS_ZS   1024
#define WS_MN   2048
#define WS_MX   18432
#define WS_CONS 34816

template<int CTRL>
__device__ __forceinline__ float dppf(float x){
  return __int_as_float(__builtin_amdgcn_update_dpp(0, __float_as_int(x), CTRL, 0xF, 0xF, true));
}
__device__ __forceinline__ float rl63(float x){
  return __int_as_float(__builtin_amdgcn_readlane(__float_as_int(x), 63));
}
__device__ __forceinline__ float wsum(float x){
  x += dppf<0x111>(x); x += dppf<0x112>(x); x += dppf<0x114>(x); x += dppf<0x118>(x);
  x += dppf<0x142>(x); x += dppf<0x143>(x);
  return rl63(x);
}

// per-k constants: {Elpk, ir*L2E, Dk*L2E, Bk*L2E}
__global__ void setup_k(const float* __restrict__ mu, const float* __restrict__ pi,
                        const float* __restrict__ rr, float* __restrict__ ws){
  int k = threadIdx.x;                       // 64 threads
  float pik = pi[k], rk = rr[k];
  float mumu = 0.f;
  #pragma unroll
  for (int d = 0; d < 16; ++d){ float m = mu[k*16+d]; mumu = fmaf(m, m, mumu); }
  float lse_pi = __logf(wsum(__expf(pik)));  // pi in [0,1]: exp safe
  float lpk = pik - lse_pi;
  float ir = __expf(-rk), Bk = -0.5f*ir;
  float Dk = fmaf(Bk, mumu, -8.f*(rk + LOG2PI_F));
  float* cons = ws + WS_CONS;
  cons[k*4+0] = __expf(lpk);
  cons[k*4+1] = ir*L2E_F;
  cons[k*4+2] = Dk*L2E_F;
  cons[k*4+3] = Bk*L2E_F;
}

// lane = row; z via per-wave [64][17] LDS tile in 4 chunks of 16 k.
// min/max pass deferred to epilogue (keeps hot-loop VGPR low; no spill at 6 waves/SIMD).
__global__ __launch_bounds__(NTHR, 6)
void zmain(const float* __restrict__ met, const float* __restrict__ mu,
           const float* __restrict__ z, float* __restrict__ ws)
{
  __shared__ float smem[4352];               // 4 wave-tiles [64][17]; reused as scr (needs 2120)
  const int tid = threadIdx.x, lane = tid & 63, wid = tid >> 6;
  const int bx = blockIdx.x;
  float* zt = smem + wid*1088;

  const int rw0 = bx*256 + wid*64;           // wave's first row
  // ---- met row into regs + ||x||^2 (lane's own row: 64B/lane, dense) ----
  const float4* xr = (const float4*)(met + (size_t)(rw0 + lane)*16);
  float4 xa = xr[0], xb = xr[1], xc = xr[2], xd = xr[3];
  float xx = 0.f;
  xx=fmaf(xa.x,xa.x,xx); xx=fmaf(xa.y,xa.y,xx); xx=fmaf(xa.z,xa.z,xx); xx=fmaf(xa.w,xa.w,xx);
  xx=fmaf(xb.x,xb.x,xx); xx=fmaf(xb.y,xb.y,xx); xx=fmaf(xb.z,xb.z,xx); xx=fmaf(xb.w,xb.w,xx);
  xx=fmaf(xc.x,xc.x,xx); xx=fmaf(xc.y,xc.y,xx); xx=fmaf(xc.z,xc.z,xx); xx=fmaf(xc.w,xc.w,xx);
  xx=fmaf(xd.x,xd.x,xx); xx=fmaf(xd.y,xd.y,xx); xx=fmaf(xd.z,xd.z,xx); xx=fmaf(xd.w,xd.w,xx);

  // ---- z chunk staging: lane l loads float4 (l&3) of tile-row (l>>2)+16i ----
  // 16 rows x 64B contiguous per inst -> full sectors, zero overfetch
  const float4* z4 = (const float4*)z;
  const int rsub = lane >> 2, kq = lane & 3;
  const float4* cons4 = (const float4*)(ws + WS_CONS);  // uniform -> s_load
  const float4* mu4   = (const float4*)mu;              // uniform -> s_load

  float sez=0.f, seu=0.f, sea=0.f, m2=-1e30f, szA=0.f;
  float4 pf0, pf1, pf2, pf3;

#define LOADC(C) { \
    pf0 = z4[(size_t)(rw0 +  0 + rsub)*16 + (C)*4 + kq]; \
    pf1 = z4[(size_t)(rw0 + 16 + rsub)*16 + (C)*4 + kq]; \
    pf2 = z4[(size_t)(rw0 + 32 + rsub)*16 + (C)*4 + kq]; \
    pf3 = z4[(size_t)(rw0 + 48 + rsub)*16 + (C)*4 + kq]; }

#define STORC() { \
    int b = rsub*17 + kq*4; \
    zt[b]=pf0.x; zt[b+1]=pf0.y; zt[b+2]=pf0.z; zt[b+3]=pf0.w; b += 272; \
    zt[b]=pf1.x; zt[b+1]=pf1.y; zt[b+2]=pf1.z; zt[b+3]=pf1.w; b += 272; \
    zt[b]=pf2.x; zt[b+1]=pf2.y; zt[b+2]=pf2.z; zt[b+3]=pf2.w; b += 272; \
    zt[b]=pf3.x; zt[b+1]=pf3.y; zt[b+2]=pf3.z; zt[b+3]=pf3.w; }

#define STEPK(K) { \
    float4 cc = cons4[K]; \
    float4 M0 = mu4[(K)*4+0], M1 = mu4[(K)*4+1], M2v = mu4[(K)*4+2], M3 = mu4[(K)*4+3]; \
    float zkv = zt[lane*17 + ((K)&15)]; \
    float zk2 = zkv*L2E_F; \
    szA += zkv; \
    sez += EXP2F(zk2); \
    seu = fmaf(cc.x, EXP2F(-0.1f*zk2), seu); \
    float dt = 0.f; \
    dt=fmaf(xa.x,M0.x,dt); dt=fmaf(xa.y,M0.y,dt); dt=fmaf(xa.z,M0.z,dt); dt=fmaf(xa.w,M0.w,dt); \
    dt=fmaf(xb.x,M1.x,dt); dt=fmaf(xb.y,M1.y,dt); dt=fmaf(xb.z,M1.z,dt); dt=fmaf(xb.w,M1.w,dt); \
    dt=fmaf(xc.x,M2v.x,dt); dt=fmaf(xc.y,M2v.y,dt); dt=fmaf(xc.z,M2v.z,dt); dt=fmaf(xc.w,M2v.w,dt); \
    dt=fmaf(xd.x,M3.x,dt); dt=fmaf(xd.y,M3.y,dt); dt=fmaf(xd.z,M3.z,dt); dt=fmaf(xd.w,M3.w,dt); \
    float t1  = fmaf(cc.w, xx, zk2); \
    float av2 = fmaf(cc.y, dt, t1) + cc.z; \
    float d2 = av2 - m2; \
    float ee = EXP2F(-fabsf(d2)); \
    bool fl = d2 > 0.f; \
    sea = fmaf(sea, fl?ee:1.f, fl?1.f:ee); \
    m2 = fmaxf(m2, av2); }

  LOADC(0)
  #pragma unroll
  for (int c = 0; c < 4; ++c){
    STORC()                                   // same-wave DS ordering vs prior chunk's reads
    if (c == 0) LOADC(1)
    else if (c == 1) LOADC(2)
    else if (c == 2) LOADC(3)
    #pragma unroll
    for (int kk = 0; kk < 16; ++kk) STEPK(c*16 + kk)
  }
#undef STEPK
#undef STORC
#undef LOADC

  // ---- per-row epilogue (base-2 logs, fold ln2 once) ----
  float accA = LN2_F * (fmaf(63.f, LOG2F(sez), m2 + LOG2F(sea)) - 64.f*LOG2F(seu));

  // ---- deferred per-dim min/max pass (met is L3-resident; regs free now) ----
  float pmn[4], pmx[4];
  #pragma unroll
  for (int j=0;j<4;++j){ pmn[j]=INFINITY; pmx[j]=-INFINITY; }
  {
    const float4* mb = (const float4*)(met + (size_t)bx*4096);
    #pragma unroll
    for (int i=0;i<4;++i){
      float4 v = mb[i*256 + tid];            // slot j tracks dim (4*tid+j)&15
      pmn[0]=fminf(pmn[0],v.x); pmx[0]=fmaxf(pmx[0],v.x);
      pmn[1]=fminf(pmn[1],v.y); pmx[1]=fmaxf(pmx[1],v.y);
      pmn[2]=fminf(pmn[2],v.z); pmx[2]=fmaxf(pmx[2],v.z);
      pmn[3]=fminf(pmn[3],v.w); pmx[3]=fmaxf(pmx[3],v.w);
    }
  }

  // ---- block reduction: reuse smem as scratch (tiles dead after barrier) ----
  __syncthreads();
  float* scr = smem;                          // smn 0..1055, smx 1056..2111, waves 2112..2119
  float wa = wsum(accA), wz = wsum(szA);
  if (lane == 0){ scr[2112 + wid] = wa; scr[2116 + wid] = wz; }
  #pragma unroll
  for (int j=0;j<4;++j){
    int d = (4*tid + j) & 15;
    scr[       d*66 + (tid>>2)] = pmn[j];
    scr[1056 + d*66 + (tid>>2)] = pmx[j];
  }
  __syncthreads();
  if (tid == 0){
    ws[bx]         = scr[2112]+scr[2113]+scr[2114]+scr[2115];
    ws[WS_ZS + bx] = scr[2116]+scr[2117]+scr[2118]+scr[2119];
  }
  if (tid < 16){
    float mnv = INFINITY, mxv = -INFINITY;
    for (int c2=0;c2<64;++c2){
      mnv = fminf(mnv, scr[tid*66+c2]);
      mxv = fmaxf(mxv, scr[1056+tid*66+c2]);
    }
    ws[WS_MN + bx*16 + tid] = mnv;
    ws[WS_MX + bx*16 + tid] = mxv;
  }
}

__global__ __launch_bounds__(NTHR)
void fin_k(const float* __restrict__ mu, const float* __restrict__ pi,
           const float* __restrict__ lam, const float* __restrict__ bp,
           const float* __restrict__ Cv,  const float* __restrict__ rr,
           const float* __restrict__ ws,  float* __restrict__ out,
           float cgam, float lamconst, float lg_c, float lg_g)
{
  __shared__ double sda[NTHR], sdz[NTHR];
  __shared__ float smn[16][66], smx[16][66];
  __shared__ float Rfin[16], vars[16];
  const int tid = threadIdx.x;

  {
    const float4* wa4 = (const float4*)ws;
    const float4* wz4 = (const float4*)(ws + WS_ZS);
    float4 a = wa4[tid], zz = wz4[tid];
    sda[tid] = (double)a.x + (double)a.y + (double)a.z + (double)a.w;
    sdz[tid] = (double)zz.x + (double)zz.y + (double)zz.z + (double)zz.w;
  }
  float pmn[4], pmx[4];
  #pragma unroll
  for (int j=0;j<4;++j){ pmn[j]=INFINITY; pmx[j]=-INFINITY; }
  {
    const float4* mn4 = (const float4*)(ws + WS_MN);
    const float4* mx4 = (const float4*)(ws + WS_MX);
    #pragma unroll
    for (int i=0;i<16;++i){
      float4 v = mn4[i*256 + tid];
      pmn[0]=fminf(pmn[0],v.x); pmn[1]=fminf(pmn[1],v.y);
      pmn[2]=fminf(pmn[2],v.z); pmn[3]=fminf(pmn[3],v.w);
      float4 w = mx4[i*256 + tid];
      pmx[0]=fmaxf(pmx[0],w.x); pmx[1]=fmaxf(pmx[1],w.y);
      pmx[2]=fmaxf(pmx[2],w.z); pmx[3]=fmaxf(pmx[3],w.w);
    }
  }
  #pragma unroll
  for (int j=0;j<4;++j){
    int d = (4*tid + j) & 15;
    smn[d][tid>>2] = pmn[j];
    smx[d][tid>>2] = pmx[j];
  }
  __syncthreads();
  for (int s = NTHR/2; s > 0; s >>= 1){
    if (tid < s){ sda[tid] += sda[tid+s]; sdz[tid] += sdz[tid+s]; }
    __syncthreads();
  }
  if (tid < 16){
    float mnv = INFINITY, mxv = -INFINITY;
    for (int c2=0;c2<64;++c2){ mnv = fminf(mnv, smn[tid][c2]); mxv = fmaxf(mxv, smx[tid][c2]); }
    float Rd = mxv - mnv;
    Rfin[tid] = Rd;
    float l = lam[tid];
    vars[tid] = l*l*Rd;
  }
  __syncthreads();

  if (tid < 64){
    int kk = tid;
    float sumR2 = 0.f;
    #pragma unroll
    for (int dd = 0; dd < 16; ++dd) sumR2 = fmaf(Rfin[dd], Rfin[dd], sumR2);
    float G = 0.025f * sqrtf(sumR2);          // c/(50g)*||R||, c=5, g=4

    float pik2 = pi[kk];
    float sp   = wsum(pik2);
    float lse2 = __logf(wsum(__expf(pik2)));
    float slogpi = sp - 64.f*lse2;

    float qsum = 0.f, slv = 0.f, bb = 0.f;
    #pragma unroll
    for (int dd = 0; dd < 16; ++dd){
      float df = mu[kk*16+dd] - bp[kk*16+dd];
      qsum += df*df / vars[dd];
      slv  += __logf(vars[dd]);
      float bv = bp[kk*16+dd];
      bb = fmaf(bv, bv, bb);
    }
    float mu_term = 0.5f*qsum + 0.5f*slv + 8.0f*LOG2PI_F;
    float rk2 = rr[kk], Ck = Cv[kk];
    float r_lp = 5.f*__logf(Ck) - 4.f*rk2 - Ck*__expf(-rk2) - lg_c;  // c=5
    float C_lp = 4.f*__logf(G)  - 3.f*Ck  - G*__expf(-Ck)  - lg_g;   // g=4
    float lam_term = 0.f;
    if (kk < 16){ float l = lam[kk]; lam_term = lamconst - 0.5f*l - 0.5f*__expf(l); }

    float per = mu_term + 0.5f*bb - r_lp - C_lp - lam_term;
    float persum = wsum(per);

    if (kk == 0){
      double zpart = sda[0] + 262144.0*(double)(cgam + slogpi) - 1.1*sdz[0];
      double tot = (double)persum
                 + (1.0 - 1.0/64.0)*(double)slogpi
                 + 512.0*(double)LOG2PI_F
                 - zpart;                     // z_loss = -zpart
      out[0] = (float)tot;
    }
  }
}

extern "C" void kernel_launch(void* const* d_in, const int* in_sizes, int n_in,
                              void* d_out, int out_size, void* d_ws, size_t ws_size,
                              hipStream_t stream) {
  const float* met = (const float*)d_in[0];
  const float* mu  = (const float*)d_in[1];
  const float* pi  = (const float*)d_in[2];
  const float* lam = (const float*)d_in[3];
  const float* bpp = (const float*)d_in[4];
  const float* Cv  = (const float*)d_in[5];
  const float* rr  = (const float*)d_in[6];
  const float* zz  = (const float*)d_in[7];
  float* out = (float*)d_out;
  float* ws  = (float*)d_ws;

  float cgam     = (float)(lgamma(64.0) + 63.0*log(0.1));
  float lamconst = (float)(0.5*log(0.5) - lgamma(0.5));
  float lg_c     = (float)lgamma(5.0);    // c = 1.25 + 15/4 = 5
  float lg_g     = (float)lgamma(4.0);    // g = 0.25 + 15/4 = 4

  setup_k<<<dim3(1), dim3(64), 0, stream>>>(mu, pi, rr, ws);
  zmain<<<dim3(NBLK), dim3(NTHR), 0, stream>>>(met, mu, zz, ws);
  fin_k<<<dim3(1), dim3(NTHR), 0, stream>>>(mu, pi, lam, bpp, Cv, rr, ws, out,
                                            cgam, lamconst, lg_c, lg_g);
}